// Round 1
// baseline (334.413 us; speedup 1.0000x reference)
//
#include <hip/hip_runtime.h>
#include <hip/hip_bf16.h>
#include <stdint.h>

// CausalConv1d: B=4, L=4096, D=2048, K=4, G=8
//   out[b,l,o] = sum_{k,i} x[b, l+k-3, g*256+i] * w[k,i,o],  g = o>>8
// Strategy: per-group GEMM via bf16 MFMA 16x16x32, implicit im2col (LDS row shift).

#define CC_L 4096
#define CC_D 2048
#define CC_I 256    // in-channels per group
#define CC_KI 1024  // K * CC_I (flattened K-dim per group)

typedef float f32x4 __attribute__((ext_vector_type(4)));
typedef __bf16 bf16x8 __attribute__((ext_vector_type(8)));

static __device__ __forceinline__ unsigned short f2bf(float f) {
    union { float f; uint32_t u; } v; v.f = f;
    uint32_t u = v.u;
    u += 0x7fffu + ((u >> 16) & 1u);   // round-to-nearest-even
    return (unsigned short)(u >> 16);
}

// Pre-pass: wt[o][k][i] = bf16(w[k][i][o]).  o:2048, k:4, i:256  -> 4 MB in d_ws.
// Coalesced 8B writes along i; scattered reads (8.4 MB total, L2/L3 absorbs).
__global__ __launch_bounds__(256) void cc_prep_w(const float* __restrict__ w,
                                                 unsigned short* __restrict__ wt) {
    int idx = blockIdx.x * 256 + threadIdx.x;   // 2048*4*64 threads
    int o   = idx >> 8;
    int rem = idx & 255;
    int k   = rem >> 6;
    int i4  = (rem & 63) << 2;
    const float* src = w + ((size_t)(k * CC_I + i4)) * CC_D + o;
    ushort4 h;
    h.x = f2bf(src[0]);
    h.y = f2bf(src[CC_D]);
    h.z = f2bf(src[2 * CC_D]);
    h.w = f2bf(src[3 * CC_D]);
    *(ushort4*)(wt + (size_t)o * CC_KI + k * CC_I + i4) = h;
}

// Main: grid = (M/128)*(D/128) = 128*16 = 2048 blocks, 256 threads (4 waves, 2x2).
// LDS stride 72 bf16 = 144 B = 36 dwords: 16B-aligned for b128, 4-bank row rotation
// -> uniform bank distribution for wave64 ds_read_b128.
__global__ __launch_bounds__(256) void cc_conv(const float* __restrict__ x,
                                               const unsigned short* __restrict__ wt,
                                               float* __restrict__ out) {
    __shared__ unsigned short As[131][72];  // x rows [l0-3 .. l0+127], 64 ch chunk
    __shared__ unsigned short Bs[128][72];  // Bs[n][kk]: w[kf][cc*64+kk][n0+n]

    const int tid   = threadIdx.x;
    const int tileN = blockIdx.x & 15;
    const int tileM = blockIdx.x >> 4;
    const int n0    = tileN << 7;           // output-channel base
    const int g     = tileN >> 1;           // group (2 N-tiles per group)
    const int cin   = g << 8;               // input-channel base of group
    const int m0    = tileM << 7;           // global row base (b*L + l)
    const int b     = m0 >> 12;             // 4096 rows per batch; tiles never span batches
    const int l0    = m0 & (CC_L - 1);

    const int lane = tid & 63;
    const int wv   = tid >> 6;
    const int wm   = (wv & 1) << 6;         // wave row base within tile
    const int wn   = (wv >> 1) << 6;        // wave col base within tile
    const int lr   = lane & 15;
    const int quad = lane >> 4;

    f32x4 acc[4][4];
#pragma unroll
    for (int i = 0; i < 4; ++i)
#pragma unroll
        for (int j = 0; j < 4; ++j) acc[i][j] = (f32x4){0.f, 0.f, 0.f, 0.f};

    for (int cc = 0; cc < 4; ++cc) {
        // ---- stage A: x[b, l0-3+r, cin + cc*64 + c] -> As[r][c], fp32->bf16 ----
        for (int idx = tid; idx < 131 * 16; idx += 256) {
            int r  = idx >> 4;
            int f4 = idx & 15;
            int l  = l0 - 3 + r;
            ushort4 h = {0, 0, 0, 0};
            if (l >= 0) {
                const float4 v = *(const float4*)(x + ((size_t)b * CC_L + l) * CC_D
                                                  + cin + (cc << 6) + (f4 << 2));
                h.x = f2bf(v.x); h.y = f2bf(v.y); h.z = f2bf(v.z); h.w = f2bf(v.w);
            }
            *(ushort4*)&As[r][f4 << 2] = h;
        }

        for (int kf = 0; kf < 4; ++kf) {
            // ---- stage B: wt[n0+n][kf][cc*64 + kk] -> Bs[n][kk] (16B copies) ----
#pragma unroll
            for (int it = 0; it < 4; ++it) {
                int idx = tid + it * 256;   // 128 rows * 8 uint4
                int n   = idx >> 3;
                int q   = idx & 7;
                const uint4 v = *(const uint4*)(wt + (size_t)(n0 + n) * CC_KI
                                                + (kf << 8) + (cc << 6) + (q << 3));
                *(uint4*)&Bs[n][q << 3] = v;
            }
            __syncthreads();   // A (kf==0) and B writes visible

#pragma unroll
            for (int ks = 0; ks < 2; ++ks) {
                bf16x8 a[4], bb[4];
#pragma unroll
                for (int f = 0; f < 4; ++f)
                    a[f] = *(const bf16x8*)&As[wm + f * 16 + lr + kf][(ks << 5) + (quad << 3)];
#pragma unroll
                for (int f = 0; f < 4; ++f)
                    bb[f] = *(const bf16x8*)&Bs[wn + f * 16 + lr][(ks << 5) + (quad << 3)];
#pragma unroll
                for (int fm = 0; fm < 4; ++fm)
#pragma unroll
                    for (int fn = 0; fn < 4; ++fn)
                        acc[fm][fn] = __builtin_amdgcn_mfma_f32_16x16x32_bf16(
                            a[fm], bb[fn], acc[fm][fn], 0, 0, 0);
            }
            __syncthreads();   // reads done before next stage overwrites
        }
    }

    // ---- epilogue: C/D layout col = lane&15, row = quad*4 + reg ----
    const size_t obase = (size_t)m0 * CC_D + n0;
#pragma unroll
    for (int fm = 0; fm < 4; ++fm)
#pragma unroll
        for (int fn = 0; fn < 4; ++fn) {
            int ml = wm + fm * 16 + quad * 4;
            int nl = wn + fn * 16 + lr;
#pragma unroll
            for (int r = 0; r < 4; ++r)
                out[obase + (size_t)(ml + r) * CC_D + nl] = acc[fm][fn][r];
        }
}

extern "C" void kernel_launch(void* const* d_in, const int* in_sizes, int n_in,
                              void* d_out, int out_size, void* d_ws, size_t ws_size,
                              hipStream_t stream) {
    const float* x = (const float*)d_in[0];
    const float* w = (const float*)d_in[1];
    float* out = (float*)d_out;
    unsigned short* wt = (unsigned short*)d_ws;   // 2048*1024 bf16 = 4 MB

    cc_prep_w<<<2048, 256, 0, stream>>>(w, wt);
    cc_conv<<<2048, 256, 0, stream>>>(x, wt, out);
}

// Round 2
// 268.191 us; speedup vs baseline: 1.2469x; 1.2469x over previous
//
#include <hip/hip_runtime.h>
#include <stdint.h>

// CausalConv1d: B=4, L=4096, D=2048, K=4, G=8
//   out[b,l,o] = sum_{k,i} x[b, l+k-3, g*256+i] * w[k,i,o],  g = o>>8
// R2: per-group GEMM via bf16 MFMA 16x16x32, implicit im2col.
//   - prep_w: LDS-transpose, coalesced both sides (was 170us uncoalesced)
//   - conv: B staged via global_load_lds(16B) + XOR swizzle (no padding allowed),
//           double-buffered; A register-prefetched 1 cc ahead; 1 barrier/k-step.

#define CC_L 4096
#define CC_D 2048

typedef float f32x4 __attribute__((ext_vector_type(4)));
typedef __bf16 bf16x8 __attribute__((ext_vector_type(8)));

static __device__ __forceinline__ unsigned short f2bf(float f) {
    union { float f; uint32_t u; } v; v.f = f;
    uint32_t u = v.u;
    u += 0x7fffu + ((u >> 16) & 1u);   // round-to-nearest-even
    return (unsigned short)(u >> 16);
}

static __device__ __forceinline__ void glds16(const void* g, void* l) {
    __builtin_amdgcn_global_load_lds(
        (const __attribute__((address_space(1))) uint32_t*)g,
        (__attribute__((address_space(3))) uint32_t*)l, 16, 0, 0);
}

// ---------------------------------------------------------------------------
// prep: wt[o][k*256+i] = bf16(w[k][i][o]).  LDS transpose tile 64o x 128i.
// grid = 4k * 32 o-tiles * 2 i-halves = 256 blocks, 256 threads.
// Reads coalesced along o (float4), writes coalesced along i (uint4).
__global__ __launch_bounds__(256) void cc_prep_w(const float* __restrict__ w,
                                                 unsigned short* __restrict__ wt) {
    __shared__ unsigned short T[64][136];   // [o_local][i_local]; 272B row = 17*16B
    const int tid = threadIdx.x;
    const int k  = blockIdx.x >> 6;
    const int ot = (blockIdx.x >> 1) & 31;
    const int ih = blockIdx.x & 1;
    const int o0 = ot << 6;
    const int i0 = ih << 7;

#pragma unroll
    for (int it = 0; it < 8; ++it) {
        int i  = it * 16 + (tid >> 4);          // 0..127
        int oc = (tid & 15) << 2;               // 0..60
        const float4 v = *(const float4*)(w + ((size_t)(k * 256 + i0 + i)) * CC_D + o0 + oc);
        T[oc + 0][i] = f2bf(v.x);
        T[oc + 1][i] = f2bf(v.y);
        T[oc + 2][i] = f2bf(v.z);
        T[oc + 3][i] = f2bf(v.w);
    }
    __syncthreads();
#pragma unroll
    for (int it = 0; it < 4; ++it) {
        int o  = it * 16 + (tid >> 4);          // 0..63
        int ic = (tid & 15) << 3;               // 0..120
        *(uint4*)(wt + (size_t)(o0 + o) * 1024 + k * 256 + i0 + ic) = *(const uint4*)&T[o][ic];
    }
}

// ---------------------------------------------------------------------------
// conv: grid = (M/128)*(D/128) = 128*16 = 2048 blocks, 256 threads (4 waves 2x2).
__global__ __launch_bounds__(256, 3) void cc_conv(const float* __restrict__ x,
                                                  const unsigned short* __restrict__ wt,
                                                  float* __restrict__ out) {
    __shared__ unsigned short As[131][72];        // padded; manual staging (fp32->bf16)
    __shared__ unsigned short Bs[2][128][64];     // unpadded; glds + XOR swizzle

    const int tid   = threadIdx.x;
    const int tileN = blockIdx.x & 15;
    const int tileM = blockIdx.x >> 4;
    const int n0    = tileN << 7;
    const int g     = tileN >> 1;
    const int cin   = g << 8;
    const int m0    = tileM << 7;
    const int b     = m0 >> 12;                   // tiles never span batches
    const int l0    = m0 & (CC_L - 1);

    const int lane = tid & 63;
    const int wv   = tid >> 6;
    const int wm   = (wv & 1) << 6;
    const int wn   = (wv >> 1) << 6;
    const int lr   = lane & 15;
    const int quad = lane >> 4;

    // B glds lane constants: LDS slot (row rowbase+(lane>>3), chunk lane&7) must
    // receive data chunk q = (lane&7) ^ ((lane>>3)&7)  [swizzle via global addr]
    const int b_row = lane >> 3;
    const int b_q   = (lane & 7) ^ b_row;

    const float* xg = x + (size_t)b * CC_L * CC_D + cin;

    f32x4 acc[4][4];
#pragma unroll
    for (int i = 0; i < 4; ++i)
#pragma unroll
        for (int j = 0; j < 4; ++j) acc[i][j] = (f32x4){0.f, 0.f, 0.f, 0.f};

    // ---- A register prefetch: main 128 rows (8 f4/thread) + 3 halo rows ----
    const int f4 = tid & 15;
    const int rb = tid >> 4;
    float4 avm[8];
    float4 avh;

#define LOAD_A(cc)                                                                  \
    {                                                                               \
        _Pragma("unroll")                                                           \
        for (int j = 0; j < 8; ++j) {                                               \
            int l = l0 + rb + j * 16;                                               \
            avm[j] = *(const float4*)(xg + (size_t)l * CC_D + ((cc) << 6) + (f4 << 2)); \
        }                                                                           \
        if (tid < 48) {                                                             \
            int l = l0 - 3 + (tid >> 4);                                            \
            avh = *(const float4*)(xg + (size_t)(l < 0 ? 0 : l) * CC_D + ((cc) << 6) + (f4 << 2)); \
        }                                                                           \
    }

#define WRITE_A()                                                                   \
    {                                                                               \
        _Pragma("unroll")                                                           \
        for (int j = 0; j < 8; ++j) {                                               \
            ushort4 h;                                                              \
            h.x = f2bf(avm[j].x); h.y = f2bf(avm[j].y);                             \
            h.z = f2bf(avm[j].z); h.w = f2bf(avm[j].w);                             \
            *(ushort4*)&As[rb + j * 16 + 3][f4 << 2] = h;                           \
        }                                                                           \
        if (tid < 48) {                                                             \
            ushort4 h = {0, 0, 0, 0};                                               \
            if (l0 > 0) {                                                           \
                h.x = f2bf(avh.x); h.y = f2bf(avh.y);                               \
                h.z = f2bf(avh.z); h.w = f2bf(avh.w);                               \
            }                                                                       \
            *(ushort4*)&As[tid >> 4][f4 << 2] = h;                                  \
        }                                                                           \
    }

#define ISSUE_B(buf, stp)                                                           \
    {                                                                               \
        const unsigned short* gb = wt + (size_t)n0 * 1024 + (((stp) & 3) << 8)      \
                                   + (((stp) >> 2) << 6);                           \
        _Pragma("unroll")                                                           \
        for (int it = 0; it < 4; ++it) {                                            \
            int rowbase = (wv << 5) + (it << 3);                                    \
            glds16(gb + (size_t)(rowbase + b_row) * 1024 + (b_q << 3),              \
                   &Bs[buf][rowbase][0]);                                           \
        }                                                                           \
    }

    // ---- prologue ----
    LOAD_A(0);
    ISSUE_B(0, 0);
    WRITE_A();          // As(0); compiler waits vmcnt for avm
    LOAD_A(1);
    __syncthreads();    // drains glds B(0); As(0) visible

    // ---- main loop: s = cc*4 + kf ----
    for (int s = 0; s < 16; ++s) {
        if (s < 15) ISSUE_B((s + 1) & 1, s + 1);
        const int kf = s & 3;
        const int pb = s & 1;
#pragma unroll
        for (int ks = 0; ks < 2; ++ks) {
            bf16x8 a[4], bb[4];
#pragma unroll
            for (int f = 0; f < 4; ++f)
                a[f] = *(const bf16x8*)&As[wm + f * 16 + lr + kf][(ks << 5) + (quad << 3)];
#pragma unroll
            for (int f = 0; f < 4; ++f) {
                int n    = wn + f * 16 + lr;
                int slot = ((ks << 2) + quad) ^ (lr & 7);
                bb[f] = *(const bf16x8*)&Bs[pb][n][slot << 3];
            }
#pragma unroll
            for (int fm = 0; fm < 4; ++fm)
#pragma unroll
                for (int fn = 0; fn < 4; ++fn)
                    acc[fm][fn] = __builtin_amdgcn_mfma_f32_16x16x32_bf16(
                        a[fm], bb[fn], acc[fm][fn], 0, 0, 0);
        }
        if (kf == 3 && s < 15) {
            __syncthreads();            // all waves done reading As(cc)
            WRITE_A();                  // As(cc+1) from regs
            int ccn = (s >> 2) + 2;
            if (ccn < 4) LOAD_A(ccn);
        }
        if (s < 15) __syncthreads();    // drains B glds for s+1; As visible
    }

    // ---- epilogue: C/D layout col = lane&15, row = quad*4 + reg ----
    const size_t obase = (size_t)m0 * CC_D + n0;
#pragma unroll
    for (int fm = 0; fm < 4; ++fm)
#pragma unroll
        for (int fn = 0; fn < 4; ++fn) {
            int ml = wm + fm * 16 + quad * 4;
            int nl = wn + fn * 16 + lr;
#pragma unroll
            for (int r = 0; r < 4; ++r)
                out[obase + (size_t)(ml + r) * CC_D + nl] = acc[fm][fn][r];
        }
}

extern "C" void kernel_launch(void* const* d_in, const int* in_sizes, int n_in,
                              void* d_out, int out_size, void* d_ws, size_t ws_size,
                              hipStream_t stream) {
    const float* x = (const float*)d_in[0];
    const float* w = (const float*)d_in[1];
    float* out = (float*)d_out;
    unsigned short* wt = (unsigned short*)d_ws;   // 2048*1024 bf16 = 4 MB

    cc_prep_w<<<256, 256, 0, stream>>>(w, wt);
    cc_conv<<<2048, 256, 0, stream>>>(x, wt, out);
}